// Round 11
// baseline (639.057 us; speedup 1.0000x reference)
//
#include <hip/hip_runtime.h>
#include <stdint.h>

#define N_SPK 512
#define N_UTT 64
#define DIM   1024
#define NROWS (N_SPK * N_UTT)   // 32768
#define EPS   1e-6f

// GEMM: 128 rows x 512 cols (FULL speaker axis) per block, BK=32,
// 8 waves (2M x 4N), wave-tile 64x128, 2-slot LDS ring (80 KB) -> 2 blocks/CU.
#define BMF 128
#define BKF 32
#define KTF (DIM / BKF)         // 32
#define SLOT_BYTES 40960        // A 8KB + B 32KB

typedef __attribute__((ext_vector_type(8))) short short8;
typedef __attribute__((ext_vector_type(4))) float f32x4;

__device__ __forceinline__ uint16_t f2bf(float f) {
    union { float f; uint32_t i; } un; un.f = f;
    uint32_t x = un.i;
    return (uint16_t)((x + 0x7fffu + ((x >> 16) & 1u)) >> 16);
}

// K1: one block per speaker (unchanged — measured at BW floor).
__global__ __launch_bounds__(256) void prep_centroid(
    const float* __restrict__ x, uint16_t* __restrict__ xb,
    uint16_t* __restrict__ cmat, float* __restrict__ xxg,
    float* __restrict__ ssqg)
{
    const int n    = blockIdx.x;
    const int tid  = threadIdx.x;
    const int lane = tid & 63;
    const int w    = tid >> 6;

    const float* xn  = x  + (size_t)n * N_UTT * DIM;
    uint16_t*    xbn = xb + (size_t)n * N_UTT * DIM;

    float Sp[16];
    #pragma unroll
    for (int j = 0; j < 16; ++j) Sp[j] = 0.f;

    #pragma unroll 1
    for (int o = 0; o < 4; ++o) {
        const int m0 = w * 16 + o * 4;

        float4 v[16];
        #pragma unroll
        for (int i = 0; i < 4; ++i)
            #pragma unroll
            for (int j = 0; j < 4; ++j)
                v[i * 4 + j] = *(const float4*)(xn + (size_t)(m0 + i) * DIM + j * 256 + lane * 4);

        float xx[4] = {0.f, 0.f, 0.f, 0.f};
        #pragma unroll
        for (int i = 0; i < 4; ++i) {
            #pragma unroll
            for (int j = 0; j < 4; ++j) {
                const float4 qv = v[i * 4 + j];
                xx[i] += qv.x * qv.x + qv.y * qv.y + qv.z * qv.z + qv.w * qv.w;
                Sp[j * 4 + 0] += qv.x; Sp[j * 4 + 1] += qv.y;
                Sp[j * 4 + 2] += qv.z; Sp[j * 4 + 3] += qv.w;
                ushort4 ov;
                ov.x = f2bf(qv.x); ov.y = f2bf(qv.y); ov.z = f2bf(qv.z); ov.w = f2bf(qv.w);
                *(ushort4*)(xbn + (size_t)(m0 + i) * DIM + j * 256 + lane * 4) = ov;
            }
        }

        #pragma unroll
        for (int i = 0; i < 4; ++i) {
            float t = xx[i];
            #pragma unroll
            for (int off = 1; off < 64; off <<= 1) t += __shfl_xor(t, off);
            if (lane == 0) xxg[n * N_UTT + m0 + i] = t;
        }
    }

    __shared__ float Sh[4][DIM];
    #pragma unroll
    for (int j = 0; j < 4; ++j)
        *(float4*)&Sh[w][j * 256 + lane * 4] =
            make_float4(Sp[j * 4], Sp[j * 4 + 1], Sp[j * 4 + 2], Sp[j * 4 + 3]);
    __syncthreads();

    const int d0 = tid * 4;
    float4 S  = *(const float4*)&Sh[0][d0];
    const float4 b1 = *(const float4*)&Sh[1][d0];
    const float4 b2 = *(const float4*)&Sh[2][d0];
    const float4 b3 = *(const float4*)&Sh[3][d0];
    S.x += b1.x + b2.x + b3.x; S.y += b1.y + b2.y + b3.y;
    S.z += b1.z + b2.z + b3.z; S.w += b1.w + b2.w + b3.w;

    float css = S.x * S.x + S.y * S.y + S.z * S.z + S.w * S.w;
    #pragma unroll
    for (int off = 1; off < 64; off <<= 1) css += __shfl_xor(css, off);
    __shared__ float red[4];
    if ((tid & 63) == 0) red[tid >> 6] = css;
    __syncthreads();
    const float ssq = red[0] + red[1] + red[2] + red[3];

    const float scale = rsqrtf(fmaxf(ssq * (1.0f / 4096.f), EPS)) * (1.0f / 64.f);
    ushort4 oc;
    oc.x = f2bf(S.x * scale); oc.y = f2bf(S.y * scale);
    oc.z = f2bf(S.z * scale); oc.w = f2bf(S.w * scale);
    *(ushort4*)(cmat + (size_t)n * DIM + d0) = oc;
    if (tid == 0) ssqg[n] = ssq;
}

// K2: full-row GEMM+LSE, r9 geometry (256 blocks, BMF=128) with the ring cut
// to 2 slots (80 KB) so 2 blocks co-reside per CU (r10 post-mortem: occupancy
// must come from LDS shrink, NOT more blocks — that doubles barrier+staging).
// Ring (depth 1): iter t: vmcnt(0) [tile-t loads issued one full compute
// phase ago] -> s_barrier [all waves' tile-t resident + iter-(t-1) reads of
// the stage target done] -> STAGE tile t+1 into other slot -> compute tile t.
// Per-iter drain cost is covered by the co-resident block (m114 overlap).
// Swizzle (r2-proven): stage kc=(s&3)^((row>>1)&3); read kcs=q^((cL>>1)&3).
__global__ __launch_bounds__(512, 4) void gemm_lse_kernel(
    const uint16_t* __restrict__ xb, const uint16_t* __restrict__ cmat,
    const float* __restrict__ xxg, const float* __restrict__ ssqg,
    const float* __restrict__ wp, const float* __restrict__ bp,
    float* __restrict__ partial)
{
    __shared__ char smem[2 * SLOT_BYTES];   // 80 KB ring; epilogue aliases base

    const int tid   = threadIdx.x;
    const int lane  = tid & 63;
    const int wid   = tid >> 6;      // 0..7
    const int waveM = wid >> 2;      // 0..1 (64 rows each)
    const int waveN = wid & 3;       // 0..3 (128 cols each)

    const int rowBase = blockIdx.x * BMF;

    // staging: 5 x 16B loads/thread/K-tile. i=0 covers A (512 slots);
    // i=1..4 cover B (2048 slots).
    const uint16_t* gsrc[5];
    int ldso[5];
    {
        const int srow = tid >> 2;
        const int kc   = (tid & 3) ^ ((srow >> 1) & 3);
        gsrc[0] = xb + (size_t)(rowBase + srow) * DIM + kc * 8;
        ldso[0] = tid * 16;
    }
    #pragma unroll
    for (int i = 1; i < 5; ++i) {
        const int s    = tid + (i - 1) * 512;     // 0..2047
        const int brow = s >> 2;                  // 0..511
        const int kc   = (s & 3) ^ ((brow >> 1) & 3);
        gsrc[i] = cmat + (size_t)brow * DIM + kc * 8;
        ldso[i] = 8192 + s * 16;
    }

#define STAGE(slot, kt_)                                                        \
    { _Pragma("unroll")                                                         \
      for (int i_ = 0; i_ < 5; ++i_) {                                          \
        __builtin_amdgcn_global_load_lds(                                       \
            (const __attribute__((address_space(1))) void*)(gsrc[i_] + (kt_) * BKF), \
            (__attribute__((address_space(3))) void*)(smem + (slot) * SLOT_BYTES + ldso[i_]), \
            16, 0, 0); } }

    f32x4 acc[4][8];
    #pragma unroll
    for (int i = 0; i < 4; ++i)
        #pragma unroll
        for (int j = 0; j < 8; ++j)
            acc[i][j] = (f32x4){0.f, 0.f, 0.f, 0.f};

    const int cL  = lane & 15;
    const int q   = lane >> 4;
    const int kcs = q ^ ((cL >> 1) & 3);

#define COMPUTE(slot_)                                                          \
    {                                                                           \
        const char* Ab_ = smem + (slot_) * SLOT_BYTES;                          \
        const char* Bb_ = smem + (slot_) * SLOT_BYTES + 8192;                   \
        short8 a_[4], b_[8];                                                    \
        _Pragma("unroll")                                                       \
        for (int bi_ = 0; bi_ < 4; ++bi_)                                       \
            a_[bi_] = *(const short8*)(Ab_ + (waveM * 64 + bi_ * 16 + cL) * 64 + kcs * 16); \
        _Pragma("unroll")                                                       \
        for (int bj_ = 0; bj_ < 8; ++bj_)                                       \
            b_[bj_] = *(const short8*)(Bb_ + (waveN * 128 + bj_ * 16 + cL) * 64 + kcs * 16); \
        __builtin_amdgcn_s_setprio(1);                                          \
        _Pragma("unroll")                                                       \
        for (int bi_ = 0; bi_ < 4; ++bi_)                                       \
            _Pragma("unroll")                                                   \
            for (int bj_ = 0; bj_ < 8; ++bj_)                                   \
                acc[bi_][bj_] = __builtin_amdgcn_mfma_f32_16x16x32_bf16(        \
                    a_[bi_], b_[bj_], acc[bi_][bj_], 0, 0, 0);                  \
        __builtin_amdgcn_s_setprio(0);                                          \
    }

#define ITER(kt_, cSlot, sSlot)                                                 \
    {                                                                           \
        asm volatile("s_waitcnt vmcnt(0)" ::: "memory");                        \
        __builtin_amdgcn_sched_barrier(0);                                      \
        __builtin_amdgcn_s_barrier();                                           \
        __builtin_amdgcn_sched_barrier(0);                                      \
        STAGE(sSlot, (kt_) + 1);                                                \
        COMPUTE(cSlot);                                                         \
    }

    // prologue: tile 0 into slot 0
    STAGE(0, 0);

    for (int tb = 0; tb < 30; tb += 2) {   // t = 0..29, stages tiles 1..30
        ITER(tb + 0, 0, 1);
        ITER(tb + 1, 1, 0);
    }
    // t = 30 (slot 0): stages tile 31 into slot 1
    ITER(30, 0, 1);
    // t = 31 (slot 1): drain
    asm volatile("s_waitcnt vmcnt(0)" ::: "memory");
    __builtin_amdgcn_sched_barrier(0);
    __builtin_amdgcn_s_barrier();
    __builtin_amdgcn_sched_barrier(0);
    COMPUTE(1);
#undef STAGE
#undef COMPUTE
#undef ITER

    // epilogue: full-row LSE in-block. Se[4][128] exp-sums, Pe[128] diag sims.
    __syncthreads();
    float* Se  = (float*)smem;                 // 2048 B
    float* Pe  = (float*)(smem + 2048);        // 512 B
    float* red = (float*)(smem + 2560);        // 8 B

    const float wv = wp[0], bv = bp[0];
    #pragma unroll
    for (int bi = 0; bi < 4; ++bi) {
        #pragma unroll
        for (int r = 0; r < 4; ++r) {
            const int lr    = waveM * 64 + bi * 16 + q * 4 + r;   // 0..127
            const int R     = rowBase + lr;
            const float xxv = xxg[R];
            const float rn  = rsqrtf(fmaxf(xxv, EPS));
            const int nrow  = R >> 6;                              // 0..511
            float s = 0.f;
            #pragma unroll
            for (int bj = 0; bj < 8; ++bj) {
                const int col = waveN * 128 + bj * 16 + cL;
                const float dot = acc[bi][bj][r];
                float sim;
                if (col == nrow) {
                    const float ssqv = ssqg[nrow];
                    const float xs   = dot * sqrtf(ssqv);
                    const float d2   = ssqv - 2.f * xs + xxv;
                    const float cs   = ((xs - xxv) * (1.f / 63.f)) * rn *
                                       rsqrtf(fmaxf(d2 * (1.f / 3969.f), EPS));
                    sim = wv * cs + bv;
                    Pe[lr] = sim;              // exactly one lane per row
                } else {
                    sim = wv * (dot * rn) + bv;
                }
                s += __expf(sim);
            }
            #pragma unroll
            for (int off = 1; off < 16; off <<= 1) s += __shfl_xor(s, off);
            if (cL == 0) Se[waveN * 128 + lr] = s;
        }
    }
    __syncthreads();
    if (tid < 128) {
        const float tot = Se[tid] + Se[128 + tid] + Se[256 + tid] + Se[384 + tid];
        float lt = __logf(tot) - Pe[tid];
        #pragma unroll
        for (int off = 1; off < 64; off <<= 1) lt += __shfl_xor(lt, off);
        if ((tid & 63) == 0) red[tid >> 6] = lt;
    }
    __syncthreads();
    if (tid == 0) partial[blockIdx.x] = red[0] + red[1];
}

// K3: single block sums the 256 per-block partials (deterministic tree).
__global__ __launch_bounds__(256) void finalize_sum(
    const float* __restrict__ partial, float* __restrict__ out)
{
    const int tid = threadIdx.x;
    float t = partial[tid];
    #pragma unroll
    for (int off = 1; off < 64; off <<= 1) t += __shfl_xor(t, off);
    __shared__ float red[4];
    if ((tid & 63) == 0) red[tid >> 6] = t;
    __syncthreads();
    if (tid == 0) out[0] = red[0] + red[1] + red[2] + red[3];
}

extern "C" void kernel_launch(void* const* d_in, const int* in_sizes, int n_in,
                              void* d_out, int out_size, void* d_ws, size_t ws_size,
                              hipStream_t stream)
{
    const float* x  = (const float*)d_in[0];
    const float* wp = (const float*)d_in[1];
    const float* bp = (const float*)d_in[2];
    float* out = (float*)d_out;

    char* ws = (char*)d_ws;
    size_t off = 0;
    uint16_t* xb      = (uint16_t*)(ws + off); off += (size_t)NROWS * DIM * 2;   // 64 MB
    uint16_t* cmat    = (uint16_t*)(ws + off); off += (size_t)N_SPK * DIM * 2;   // 1 MB
    float*    xxg     = (float*)(ws + off);    off += (size_t)NROWS * 4;
    float*    ssqg    = (float*)(ws + off);    off += (size_t)N_SPK * 4;
    float*    partial = (float*)(ws + off);    off += (size_t)256 * 4;

    prep_centroid<<<N_SPK, 256, 0, stream>>>(x, xb, cmat, xxg, ssqg);
    gemm_lse_kernel<<<NROWS / BMF, 512, 0, stream>>>(
        xb, cmat, xxg, ssqg, wp, bp, partial);
    finalize_sum<<<1, 256, 0, stream>>>(partial, out);
}

// Round 12
// 243.969 us; speedup vs baseline: 2.6194x; 2.6194x over previous
//
#include <hip/hip_runtime.h>
#include <stdint.h>

#define N_SPK 512
#define N_UTT 64
#define DIM   1024
#define NROWS (N_SPK * N_UTT)   // 32768
#define EPS   1e-6f

// GEMM: 128 rows x 512 cols (FULL speaker axis) per block, BK=32,
// 8 waves (2M x 4N), wave-tile 64x128, 3-slot LDS ring, counted vmcnt.
// NOTE (r11 lesson): do NOT add __launch_bounds__ min-waves here — the
// unified VGPR/AGPR file means acc[4][8] (128 regs) + addressing cannot fit
// a 128-reg/2-blocks-per-CU budget; forcing it spills the accumulator
// (r11: VGPR=64, 1.3GB scratch traffic, 449µs).
#define BMF 128
#define BKF 32
#define KTF (DIM / BKF)         // 32
#define SLOT_BYTES 40960        // A 8KB + B 32KB

typedef __attribute__((ext_vector_type(8))) short short8;
typedef __attribute__((ext_vector_type(4))) float f32x4;

__device__ __forceinline__ uint16_t f2bf(float f) {
    union { float f; uint32_t i; } un; un.f = f;
    uint32_t x = un.i;
    return (uint16_t)((x + 0x7fffu + ((x >> 16) & 1u)) >> 16);
}

// K1: one block per speaker (measured at BW floor).
__global__ __launch_bounds__(256) void prep_centroid(
    const float* __restrict__ x, uint16_t* __restrict__ xb,
    uint16_t* __restrict__ cmat, float* __restrict__ xxg,
    float* __restrict__ ssqg)
{
    const int n    = blockIdx.x;
    const int tid  = threadIdx.x;
    const int lane = tid & 63;
    const int w    = tid >> 6;

    const float* xn  = x  + (size_t)n * N_UTT * DIM;
    uint16_t*    xbn = xb + (size_t)n * N_UTT * DIM;

    float Sp[16];
    #pragma unroll
    for (int j = 0; j < 16; ++j) Sp[j] = 0.f;

    #pragma unroll 1
    for (int o = 0; o < 4; ++o) {
        const int m0 = w * 16 + o * 4;

        float4 v[16];
        #pragma unroll
        for (int i = 0; i < 4; ++i)
            #pragma unroll
            for (int j = 0; j < 4; ++j)
                v[i * 4 + j] = *(const float4*)(xn + (size_t)(m0 + i) * DIM + j * 256 + lane * 4);

        float xx[4] = {0.f, 0.f, 0.f, 0.f};
        #pragma unroll
        for (int i = 0; i < 4; ++i) {
            #pragma unroll
            for (int j = 0; j < 4; ++j) {
                const float4 qv = v[i * 4 + j];
                xx[i] += qv.x * qv.x + qv.y * qv.y + qv.z * qv.z + qv.w * qv.w;
                Sp[j * 4 + 0] += qv.x; Sp[j * 4 + 1] += qv.y;
                Sp[j * 4 + 2] += qv.z; Sp[j * 4 + 3] += qv.w;
                ushort4 ov;
                ov.x = f2bf(qv.x); ov.y = f2bf(qv.y); ov.z = f2bf(qv.z); ov.w = f2bf(qv.w);
                *(ushort4*)(xbn + (size_t)(m0 + i) * DIM + j * 256 + lane * 4) = ov;
            }
        }

        #pragma unroll
        for (int i = 0; i < 4; ++i) {
            float t = xx[i];
            #pragma unroll
            for (int off = 1; off < 64; off <<= 1) t += __shfl_xor(t, off);
            if (lane == 0) xxg[n * N_UTT + m0 + i] = t;
        }
    }

    __shared__ float Sh[4][DIM];
    #pragma unroll
    for (int j = 0; j < 4; ++j)
        *(float4*)&Sh[w][j * 256 + lane * 4] =
            make_float4(Sp[j * 4], Sp[j * 4 + 1], Sp[j * 4 + 2], Sp[j * 4 + 3]);
    __syncthreads();

    const int d0 = tid * 4;
    float4 S  = *(const float4*)&Sh[0][d0];
    const float4 b1 = *(const float4*)&Sh[1][d0];
    const float4 b2 = *(const float4*)&Sh[2][d0];
    const float4 b3 = *(const float4*)&Sh[3][d0];
    S.x += b1.x + b2.x + b3.x; S.y += b1.y + b2.y + b3.y;
    S.z += b1.z + b2.z + b3.z; S.w += b1.w + b2.w + b3.w;

    float css = S.x * S.x + S.y * S.y + S.z * S.z + S.w * S.w;
    #pragma unroll
    for (int off = 1; off < 64; off <<= 1) css += __shfl_xor(css, off);
    __shared__ float red[4];
    if ((tid & 63) == 0) red[tid >> 6] = css;
    __syncthreads();
    const float ssq = red[0] + red[1] + red[2] + red[3];

    const float scale = rsqrtf(fmaxf(ssq * (1.0f / 4096.f), EPS)) * (1.0f / 64.f);
    ushort4 oc;
    oc.x = f2bf(S.x * scale); oc.y = f2bf(S.y * scale);
    oc.z = f2bf(S.z * scale); oc.w = f2bf(S.w * scale);
    *(ushort4*)(cmat + (size_t)n * DIM + d0) = oc;
    if (tid == 0) ssqg[n] = ssq;
}

// K2: full-row GEMM+LSE (r7/r9 best-measured configuration, restored).
// Each block: 128 rows x ALL 512 cols -> row exp-sum + diagonal complete
// in-block -> one float out per block.
// Schedule: 3-slot ring, per iter t: vmcnt(5) [own tile-t loads done, FIFO:
// 5 newer loads = tile t+1] -> s_barrier [all waves' tile-t resident + all
// iter-(t-1) reads done] -> STAGE tile t+2 into slot (t+2)%3 == (t-1)%3 ->
// ds_read+MFMA tile t. Tail: vmcnt(5) @30, vmcnt(0) @31.
// Swizzle: stage kc=(s&3)^((row>>1)&3); read kcs=q^((cL>>1)&3)
// -> 2-way bank aliasing on ds_read_b128 (free, m136).
__global__ __launch_bounds__(512, 1) void gemm_lse_kernel(
    const uint16_t* __restrict__ xb, const uint16_t* __restrict__ cmat,
    const float* __restrict__ xxg, const float* __restrict__ ssqg,
    const float* __restrict__ wp, const float* __restrict__ bp,
    float* __restrict__ partial)
{
    __shared__ char smem[3 * SLOT_BYTES];   // 120 KB ring; epilogue aliases base

    const int tid   = threadIdx.x;
    const int lane  = tid & 63;
    const int wid   = tid >> 6;      // 0..7
    const int waveM = wid >> 2;      // 0..1 (64 rows each)
    const int waveN = wid & 3;       // 0..3 (128 cols each)

    const int rowBase = blockIdx.x * BMF;

    // staging: 5 x 16B loads/thread/K-tile. i=0 covers A (512 slots);
    // i=1..4 cover B (2048 slots).
    const uint16_t* gsrc[5];
    int ldso[5];
    {
        const int srow = tid >> 2;
        const int kc   = (tid & 3) ^ ((srow >> 1) & 3);
        gsrc[0] = xb + (size_t)(rowBase + srow) * DIM + kc * 8;
        ldso[0] = tid * 16;
    }
    #pragma unroll
    for (int i = 1; i < 5; ++i) {
        const int s    = tid + (i - 1) * 512;     // 0..2047
        const int brow = s >> 2;                  // 0..511
        const int kc   = (s & 3) ^ ((brow >> 1) & 3);
        gsrc[i] = cmat + (size_t)brow * DIM + kc * 8;
        ldso[i] = 8192 + s * 16;
    }

#define STAGE(slot, kt_)                                                        \
    { _Pragma("unroll")                                                         \
      for (int i_ = 0; i_ < 5; ++i_) {                                          \
        __builtin_amdgcn_global_load_lds(                                       \
            (const __attribute__((address_space(1))) void*)(gsrc[i_] + (kt_) * BKF), \
            (__attribute__((address_space(3))) void*)(smem + (slot) * SLOT_BYTES + ldso[i_]), \
            16, 0, 0); } }

    f32x4 acc[4][8];
    #pragma unroll
    for (int i = 0; i < 4; ++i)
        #pragma unroll
        for (int j = 0; j < 8; ++j)
            acc[i][j] = (f32x4){0.f, 0.f, 0.f, 0.f};

    const int cL  = lane & 15;
    const int q   = lane >> 4;
    const int kcs = q ^ ((cL >> 1) & 3);

#define COMPUTE(slot_)                                                          \
    {                                                                           \
        const char* Ab_ = smem + (slot_) * SLOT_BYTES;                          \
        const char* Bb_ = smem + (slot_) * SLOT_BYTES + 8192;                   \
        short8 a_[4], b_[8];                                                    \
        _Pragma("unroll")                                                       \
        for (int bi_ = 0; bi_ < 4; ++bi_)                                       \
            a_[bi_] = *(const short8*)(Ab_ + (waveM * 64 + bi_ * 16 + cL) * 64 + kcs * 16); \
        _Pragma("unroll")                                                       \
        for (int bj_ = 0; bj_ < 8; ++bj_)                                       \
            b_[bj_] = *(const short8*)(Bb_ + (waveN * 128 + bj_ * 16 + cL) * 64 + kcs * 16); \
        __builtin_amdgcn_s_setprio(1);                                          \
        _Pragma("unroll")                                                       \
        for (int bi_ = 0; bi_ < 4; ++bi_)                                       \
            _Pragma("unroll")                                                   \
            for (int bj_ = 0; bj_ < 8; ++bj_)                                   \
                acc[bi_][bj_] = __builtin_amdgcn_mfma_f32_16x16x32_bf16(        \
                    a_[bi_], b_[bj_], acc[bi_][bj_], 0, 0, 0);                  \
        __builtin_amdgcn_s_setprio(0);                                          \
    }

#define ITER(kt_, cSlot, sSlot)                                                 \
    {                                                                           \
        asm volatile("s_waitcnt vmcnt(5)" ::: "memory");                        \
        __builtin_amdgcn_sched_barrier(0);                                      \
        __builtin_amdgcn_s_barrier();                                           \
        __builtin_amdgcn_sched_barrier(0);                                      \
        STAGE(sSlot, (kt_) + 2);                                                \
        COMPUTE(cSlot);                                                         \
    }

    // prologue: tiles 0,1 in flight (10 loads/thread)
    STAGE(0, 0);
    STAGE(1, 1);

    for (int tb = 0; tb < 30; tb += 3) {   // t = 0..29
        ITER(tb + 0, 0, 2);
        ITER(tb + 1, 1, 0);
        ITER(tb + 2, 2, 1);
    }
    // t = 30 (slot 0): tile 31's 5 loads outstanding -> vmcnt(5)
    asm volatile("s_waitcnt vmcnt(5)" ::: "memory");
    __builtin_amdgcn_sched_barrier(0);
    __builtin_amdgcn_s_barrier();
    __builtin_amdgcn_sched_barrier(0);
    COMPUTE(0);
    // t = 31 (slot 1): drain
    asm volatile("s_waitcnt vmcnt(0)" ::: "memory");
    __builtin_amdgcn_sched_barrier(0);
    __builtin_amdgcn_s_barrier();
    __builtin_amdgcn_sched_barrier(0);
    COMPUTE(1);
#undef STAGE
#undef COMPUTE
#undef ITER

    // epilogue: full-row LSE in-block. Se[4][128] exp-sums, Pe[128] diag sims.
    __syncthreads();
    float* Se  = (float*)smem;                 // 2048 B
    float* Pe  = (float*)(smem + 2048);        // 512 B
    float* red = (float*)(smem + 2560);        // 8 B

    const float wv = wp[0], bv = bp[0];
    #pragma unroll
    for (int bi = 0; bi < 4; ++bi) {
        #pragma unroll
        for (int r = 0; r < 4; ++r) {
            const int lr    = waveM * 64 + bi * 16 + q * 4 + r;   // 0..127
            const int R     = rowBase + lr;
            const float xxv = xxg[R];
            const float rn  = rsqrtf(fmaxf(xxv, EPS));
            const int nrow  = R >> 6;                              // 0..511
            float s = 0.f;
            #pragma unroll
            for (int bj = 0; bj < 8; ++bj) {
                const int col = waveN * 128 + bj * 16 + cL;
                const float dot = acc[bi][bj][r];
                float sim;
                if (col == nrow) {
                    const float ssqv = ssqg[nrow];
                    const float xs   = dot * sqrtf(ssqv);
                    const float d2   = ssqv - 2.f * xs + xxv;
                    const float cs   = ((xs - xxv) * (1.f / 63.f)) * rn *
                                       rsqrtf(fmaxf(d2 * (1.f / 3969.f), EPS));
                    sim = wv * cs + bv;
                    Pe[lr] = sim;              // exactly one lane per row
                } else {
                    sim = wv * (dot * rn) + bv;
                }
                s += __expf(sim);
            }
            #pragma unroll
            for (int off = 1; off < 16; off <<= 1) s += __shfl_xor(s, off);
            if (cL == 0) Se[waveN * 128 + lr] = s;
        }
    }
    __syncthreads();
    if (tid < 128) {
        const float tot = Se[tid] + Se[128 + tid] + Se[256 + tid] + Se[384 + tid];
        float lt = __logf(tot) - Pe[tid];
        #pragma unroll
        for (int off = 1; off < 64; off <<= 1) lt += __shfl_xor(lt, off);
        if ((tid & 63) == 0) red[tid >> 6] = lt;
    }
    __syncthreads();
    if (tid == 0) partial[blockIdx.x] = red[0] + red[1];
}

// K3: single block sums the 256 per-block partials (deterministic tree).
__global__ __launch_bounds__(256) void finalize_sum(
    const float* __restrict__ partial, float* __restrict__ out)
{
    const int tid = threadIdx.x;
    float t = partial[tid];
    #pragma unroll
    for (int off = 1; off < 64; off <<= 1) t += __shfl_xor(t, off);
    __shared__ float red[4];
    if ((tid & 63) == 0) red[tid >> 6] = t;
    __syncthreads();
    if (tid == 0) out[0] = red[0] + red[1] + red[2] + red[3];
}

extern "C" void kernel_launch(void* const* d_in, const int* in_sizes, int n_in,
                              void* d_out, int out_size, void* d_ws, size_t ws_size,
                              hipStream_t stream)
{
    const float* x  = (const float*)d_in[0];
    const float* wp = (const float*)d_in[1];
    const float* bp = (const float*)d_in[2];
    float* out = (float*)d_out;

    char* ws = (char*)d_ws;
    size_t off = 0;
    uint16_t* xb      = (uint16_t*)(ws + off); off += (size_t)NROWS * DIM * 2;   // 64 MB
    uint16_t* cmat    = (uint16_t*)(ws + off); off += (size_t)N_SPK * DIM * 2;   // 1 MB
    float*    xxg     = (float*)(ws + off);    off += (size_t)NROWS * 4;
    float*    ssqg    = (float*)(ws + off);    off += (size_t)N_SPK * 4;
    float*    partial = (float*)(ws + off);    off += (size_t)256 * 4;

    prep_centroid<<<N_SPK, 256, 0, stream>>>(x, xb, cmat, xxg, ssqg);
    gemm_lse_kernel<<<NROWS / BMF, 512, 0, stream>>>(
        xb, cmat, xxg, ssqg, wp, bp, partial);
    finalize_sum<<<1, 256, 0, stream>>>(partial, out);
}